// Round 4
// baseline (581.489 us; speedup 1.0000x reference)
//
#include <hip/hip_runtime.h>

#define C_CH  128
#define NP    32768
#define K_PWL 20
#define LAT   8
#define HID   8
#define SLOTS 32
#define T_ITER 8        // tiles per block in pass1 (512 points each)

__device__ __forceinline__ float fast_tanh(float x) {
    float e = __expf(2.0f * x);                         // v_mul + v_exp_f32
    return fmaf(-2.0f, __builtin_amdgcn_rcpf(e + 1.0f), 1.0f);  // approx rcp
}

// monotone float<->uint encoding for atomic min/max on floats
__device__ __forceinline__ unsigned fenc(float f) {
    unsigned u = __float_as_uint(f);
    return (u & 0x80000000u) ? ~u : (u | 0x80000000u);
}
__device__ __forceinline__ float fdec(unsigned e) {
    unsigned u = (e & 0x80000000u) ? (e ^ 0x80000000u) : ~e;
    return __uint_as_float(u);
}

// one launch: init stats + per-channel yp generation (128 channels, 1 block)
__global__ void prep(const float* __restrict__ zf,
                     const float* __restrict__ Wf1, const float* __restrict__ bf1,
                     const float* __restrict__ Wf2, const float* __restrict__ bf2,
                     const unsigned char* __restrict__ dirs_raw,
                     float* __restrict__ ypw,
                     unsigned* cminE, unsigned* cmaxE, double* sums) {
    int t = threadIdx.x;
    if (t < C_CH) { cminE[t] = 0xFFFFFFFFu; cmaxE[t] = 0u; }
    if (t < 2 * SLOTS) sums[t] = 0.0;

    __shared__ int is_i32;
    if (t == 0) {
        // detect bool storage: int32 words (all 0/1) vs uint8 bytes
        const int* di = (const int*)dirs_raw;
        int ok = 1;
        for (int i = 0; i < 32; i++) { int v = di[i]; if (v != 0 && v != 1) ok = 0; }
        is_i32 = ok;
    }
    __syncthreads();
    if (t >= C_CH) return;
    int c = t;

    float z[LAT];
    #pragma unroll
    for (int l = 0; l < LAT; l++) z[l] = zf[c * LAT + l];
    float h[HID];
    #pragma unroll
    for (int j = 0; j < HID; j++) {
        float a = bf1[j];
        #pragma unroll
        for (int l = 0; l < LAT; l++) a = fmaf(z[l], Wf1[l * HID + j], a);
        h[j] = fast_tanh(a);
    }
    float p[K_PWL];
    #pragma unroll
    for (int k = 0; k < K_PWL; k++) {
        float a = bf2[k];
        #pragma unroll
        for (int j = 0; j < HID; j++) a = fmaf(h[j], Wf2[j * K_PWL + k], a);
        p[k] = fast_tanh(a);
    }
    // insertion sort ascending (20 elems)
    for (int i = 1; i < K_PWL; i++) {
        float key = p[i];
        int j = i - 1;
        while (j >= 0 && p[j] > key) { p[j + 1] = p[j]; j--; }
        p[j + 1] = key;
    }
    int dir = is_i32 ? (((const int*)dirs_raw)[c] != 0) : (dirs_raw[c] != 0);
    for (int k = 0; k < K_PWL; k++)
        ypw[c * K_PWL + k] = dir ? p[k] : p[K_PWL - 1 - k];
}

// grid: (NP/(T_ITER*512), C). Looped + register-double-buffered: each block
// processes T_ITER tiles of 512 points (2 points/thread), prefetching the
// next tile's inputs (global->VGPR) during current compute. Weights in LDS,
// transposed [j][l] so each j-step is 4 broadcast ds_read_b128.
__global__ __launch_bounds__(256, 4)
void pass1(const float* __restrict__ zx, const float* __restrict__ ze,
           const float* __restrict__ Wx1, const float* __restrict__ bx1,
           const float* __restrict__ Wx2, const float* __restrict__ bx2,
           const float* __restrict__ We1, const float* __restrict__ be1,
           const float* __restrict__ We2, const float* __restrict__ be2,
           float2* __restrict__ xe,
           unsigned* __restrict__ cminE, unsigned* __restrict__ cmaxE,
           double* __restrict__ sums) {
    __shared__ __align__(16) float swx1[HID][LAT];   // [j][l] transposed
    __shared__ __align__(16) float swe1[HID][LAT];
    __shared__ float sbx1[HID], swx2[HID], sbe1[HID], swe2[HID];
    __shared__ float sb2[2];    // bx2, be2

    int t = threadIdx.x;
    if (t < 64)        { swx1[t & 7][t >> 3] = Wx1[t]; }              // Wx1[l*8+j]
    else if (t < 128)  { int u = t - 64; swe1[u & 7][u >> 3] = We1[u]; }
    else if (t < 136)  sbx1[t - 128] = bx1[t - 128];
    else if (t < 144)  swx2[t - 136] = Wx2[t - 136];
    else if (t < 152)  sbe1[t - 144] = be1[t - 144];
    else if (t < 160)  swe2[t - 152] = We2[t - 152];
    else if (t == 160) sb2[0] = bx2[0];
    else if (t == 161) sb2[1] = be2[0];
    __syncthreads();

    int c = blockIdx.y;
    size_t row = (size_t)c * NP;
    int base = blockIdx.x * (T_ITER * 512);
    const float4* zx4 = (const float4*)(zx + (row + base) * LAT);
    const float4* ze4 = (const float4*)(ze + (row + base) * LAT);

    // prefetch registers (next tile): 2 points x (2 float4 zx + 2 float4 ze)
    float4 nx0a, nx0b, nx1a, nx1b, ne0a, ne0b, ne1a, ne1b;
    {
        int qa = 2 * t, qb = 512 + 2 * t;
        nx0a = zx4[qa]; nx0b = zx4[qa + 1];
        nx1a = zx4[qb]; nx1b = zx4[qb + 1];
        ne0a = ze4[qa]; ne0b = ze4[qa + 1];
        ne1a = ze4[qb]; ne1b = ze4[qb + 1];
    }

    float bx2s = sb2[0], be2s = sb2[1];
    float mn = 1e30f, mx = -1e30f, s = 0.f, s2 = 0.f;

    #pragma unroll 1
    for (int i = 0; i < T_ITER; i++) {
        // rotate prefetch -> current
        float4 cx0a = nx0a, cx0b = nx0b, cx1a = nx1a, cx1b = nx1b;
        float4 ce0a = ne0a, ce0b = ne0b, ce1a = ne1a, ce1b = ne1b;
        if (i + 1 < T_ITER) {
            int qa = (i + 1) * 1024 + 2 * t;
            int qb = qa + 512;
            nx0a = zx4[qa]; nx0b = zx4[qa + 1];
            nx1a = zx4[qb]; nx1b = zx4[qb + 1];
            ne0a = ze4[qa]; ne0b = ze4[qa + 1];
            ne1a = ze4[qb]; ne1b = ze4[qb + 1];
        }

        float xa0 = bx2s, xa1 = bx2s, ea0 = be2s, ea1 = be2s;
        #pragma unroll
        for (int j = 0; j < HID; j++) {
            float4 wxa = *(const float4*)&swx1[j][0];
            float4 wxb = *(const float4*)&swx1[j][4];
            float4 wea = *(const float4*)&swe1[j][0];
            float4 web = *(const float4*)&swe1[j][4];
            float hx0 = sbx1[j], hx1 = hx0;
            float he0 = sbe1[j], he1 = he0;
            hx0 = fmaf(cx0a.x, wxa.x, hx0); hx0 = fmaf(cx0a.y, wxa.y, hx0);
            hx0 = fmaf(cx0a.z, wxa.z, hx0); hx0 = fmaf(cx0a.w, wxa.w, hx0);
            hx0 = fmaf(cx0b.x, wxb.x, hx0); hx0 = fmaf(cx0b.y, wxb.y, hx0);
            hx0 = fmaf(cx0b.z, wxb.z, hx0); hx0 = fmaf(cx0b.w, wxb.w, hx0);
            hx1 = fmaf(cx1a.x, wxa.x, hx1); hx1 = fmaf(cx1a.y, wxa.y, hx1);
            hx1 = fmaf(cx1a.z, wxa.z, hx1); hx1 = fmaf(cx1a.w, wxa.w, hx1);
            hx1 = fmaf(cx1b.x, wxb.x, hx1); hx1 = fmaf(cx1b.y, wxb.y, hx1);
            hx1 = fmaf(cx1b.z, wxb.z, hx1); hx1 = fmaf(cx1b.w, wxb.w, hx1);
            he0 = fmaf(ce0a.x, wea.x, he0); he0 = fmaf(ce0a.y, wea.y, he0);
            he0 = fmaf(ce0a.z, wea.z, he0); he0 = fmaf(ce0a.w, wea.w, he0);
            he0 = fmaf(ce0b.x, web.x, he0); he0 = fmaf(ce0b.y, web.y, he0);
            he0 = fmaf(ce0b.z, web.z, he0); he0 = fmaf(ce0b.w, web.w, he0);
            he1 = fmaf(ce1a.x, wea.x, he1); he1 = fmaf(ce1a.y, wea.y, he1);
            he1 = fmaf(ce1a.z, wea.z, he1); he1 = fmaf(ce1a.w, wea.w, he1);
            he1 = fmaf(ce1b.x, web.x, he1); he1 = fmaf(ce1b.y, web.y, he1);
            he1 = fmaf(ce1b.z, web.z, he1); he1 = fmaf(ce1b.w, web.w, he1);
            xa0 = fmaf(fast_tanh(hx0), swx2[j], xa0);
            xa1 = fmaf(fast_tanh(hx1), swx2[j], xa1);
            ea0 = fmaf(fast_tanh(he0), swe2[j], ea0);
            ea1 = fmaf(fast_tanh(he1), swe2[j], ea1);
        }
        float xv0 = fast_tanh(xa0), xv1 = fast_tanh(xa1);
        float ev0 = fast_tanh(ea0), ev1 = fast_tanh(ea1);

        int n = base + i * 512 + t;
        xe[row + n]       = make_float2(xv0, ev0);
        xe[row + n + 256] = make_float2(xv1, ev1);

        mn = fminf(mn, fminf(xv0, xv1));
        mx = fmaxf(mx, fmaxf(xv0, xv1));
        s  += ev0 + ev1;
        s2 += fmaf(ev0, ev0, ev1 * ev1);
    }

    // block reduction: min/max(x), sum/sumsq(e)
    #pragma unroll
    for (int o = 32; o > 0; o >>= 1) {
        mn = fminf(mn, __shfl_down(mn, o));
        mx = fmaxf(mx, __shfl_down(mx, o));
        s += __shfl_down(s, o);
        s2 += __shfl_down(s2, o);
    }
    __shared__ float rmn[4], rmx[4], rs[4], rs2[4];
    int wave = t >> 6, lane = t & 63;
    if (lane == 0) { rmn[wave] = mn; rmx[wave] = mx; rs[wave] = s; rs2[wave] = s2; }
    __syncthreads();
    if (t == 0) {
        for (int w = 1; w < 4; w++) {
            mn = fminf(mn, rmn[w]); mx = fmaxf(mx, rmx[w]);
            s += rs[w]; s2 += rs2[w];
        }
        atomicMin(&cminE[c], fenc(mn));
        atomicMax(&cmaxE[c], fenc(mx));
        int slot = (blockIdx.x + blockIdx.y) & (SLOTS - 1);
        atomicAdd(&sums[2 * slot], (double)s);
        atomicAdd(&sums[2 * slot + 1], (double)s2);
    }
}

// grid: NP/32 blocks. Tile = all 128 channels x 32 points; LDS transpose for
// coalesced [N,C] output stores.
__global__ __launch_bounds__(256)
void pass2(const float2* __restrict__ xe, const float* __restrict__ ypw,
           const unsigned* __restrict__ cminE, const unsigned* __restrict__ cmaxE,
           const double* __restrict__ sums,
           float* __restrict__ out) {
    __shared__ float ytile[C_CH * 33];
    __shared__ float syp[C_CH * K_PWL];
    __shared__ float smin[C_CH], sinv[C_CH];
    __shared__ float sstat[2];   // mean, 0.1/std

    int t = threadIdx.x;
    for (int i = t; i < C_CH * K_PWL; i += 256) syp[i] = ypw[i];
    if (t < C_CH) {
        float mn = fdec(cminE[t]);
        float mx = fdec(cmaxE[t]);
        smin[t] = mn;
        sinv[t] = __builtin_amdgcn_rcpf(mx - mn);
    }
    if (t == 0) {
        double sd = 0.0, sd2 = 0.0;
        for (int i = 0; i < SLOTS; i++) { sd += sums[2 * i]; sd2 += sums[2 * i + 1]; }
        double M = (double)C_CH * NP;
        double mean = sd / M;
        double var = (sd2 - sd * sd / M) / (M - 1.0);
        sstat[0] = (float)mean;
        sstat[1] = (float)(0.1 / sqrt(var));
    }
    __syncthreads();

    const float INV_DENOM = 1.0f / (1.0f / 19.0f + 1e-7f);
    float mean = sstat[0], escale = sstat[1];
    int n0 = blockIdx.x * 32;

    #pragma unroll
    for (int i = 0; i < 16; i++) {
        int idx = i * 256 + t;
        int c = idx >> 5;
        int j = idx & 31;
        float2 v = xe[(size_t)c * NP + (n0 + j)];
        float xn = (v.x - smin[c]) * sinv[c];
        int seg = (int)floorf(xn * 19.0f);
        seg = max(0, min(18, seg));
        float y0 = syp[c * K_PWL + seg];
        float y1 = syp[c * K_PWL + seg + 1];
        float y = fmaf((xn - (float)seg * (1.0f / 19.0f)) * INV_DENOM, y1 - y0, y0);
        y = fmaf(v.y - mean, escale, y);
        ytile[c * 33 + j] = y;
    }
    __syncthreads();
    #pragma unroll
    for (int i = 0; i < 16; i++) {
        int idx = i * 256 + t;
        int j = idx >> 7;
        int c = idx & 127;
        out[(size_t)(n0 + j) * C_CH + c] = ytile[c * 33 + j];
    }
}

extern "C" void kernel_launch(void* const* d_in, const int* in_sizes, int n_in,
                              void* d_out, int out_size, void* d_ws, size_t ws_size,
                              hipStream_t stream) {
    const float* zf  = (const float*)d_in[0];
    const float* zx  = (const float*)d_in[1];
    const float* ze  = (const float*)d_in[2];
    const float* Wx1 = (const float*)d_in[3];
    const float* bx1 = (const float*)d_in[4];
    const float* Wx2 = (const float*)d_in[5];
    const float* bx2 = (const float*)d_in[6];
    const float* We1 = (const float*)d_in[7];
    const float* be1 = (const float*)d_in[8];
    const float* We2 = (const float*)d_in[9];
    const float* be2 = (const float*)d_in[10];
    const float* Wf1 = (const float*)d_in[11];
    const float* bf1 = (const float*)d_in[12];
    const float* Wf2 = (const float*)d_in[13];
    const float* bf2 = (const float*)d_in[14];
    const unsigned char* dirs = (const unsigned char*)d_in[15];

    float2* xe  = (float2*)d_ws;                       // [C, N] packed {x,e}
    float*  ypw = (float*)(xe + (size_t)C_CH * NP);
    unsigned* cminE = (unsigned*)(ypw + C_CH * K_PWL);
    unsigned* cmaxE = cminE + C_CH;
    double* sums = (double*)(cmaxE + C_CH);            // 8-aligned offset

    hipLaunchKernelGGL(prep, dim3(1), dim3(256), 0, stream,
                       zf, Wf1, bf1, Wf2, bf2, dirs, ypw, cminE, cmaxE, sums);
    hipLaunchKernelGGL(pass1, dim3(NP / (T_ITER * 512), C_CH), dim3(256), 0, stream,
                       zx, ze, Wx1, bx1, Wx2, bx2, We1, be1, We2, be2,
                       xe, cminE, cmaxE, sums);
    hipLaunchKernelGGL(pass2, dim3(NP / 32), dim3(256), 0, stream,
                       xe, ypw, cminE, cmaxE, sums, (float*)d_out);
}